// Round 2
// baseline (219.075 us; speedup 1.0000x reference)
//
#include <hip/hip_runtime.h>

#define DEV __device__ __forceinline__

constexpr int A_ = 64, DE = 128, M_ = 512;

DEV float wred_sum64(float v) {
#pragma unroll
    for (int o = 1; o < 64; o <<= 1) v += __shfl_xor(v, o, 64);
    return v;
}

// ---------------- Kernel 1: per-(b,m) hyperbolic dH2 + log_map ----------------
// one wave per (b,m) row; lane = dim (dh=64)
__global__ __launch_bounds__(256) void k_hyp(const float* __restrict__ curr_hyp,
                                             const float* __restrict__ demo_hyp,
                                             float* __restrict__ dH2,
                                             float* __restrict__ logv) {
    const int lane = threadIdx.x & 63;
    const int r    = (blockIdx.x << 2) + (threadIdx.x >> 6);  // [0, B*M)
    const int b    = r >> 9;                                  // M=512

    float x = curr_hyp[(b << 6) + lane];
    float y = demo_hyp[((size_t)r << 6) + lane];
    const float mx = 1.0f - 1e-5f;

    // project x to ball
    float x2r = wred_sum64(x * x);
    float xn  = fmaxf(sqrtf(x2r), 1e-15f);
    float sx  = xn > mx ? mx / xn : 1.0f;
    x *= sx;
    float x2 = x2r * sx * sx;
    // project y
    float y2r = wred_sum64(y * y);
    float yn  = fmaxf(sqrtf(y2r), 1e-15f);
    float sy  = yn > mx ? mx / yn : 1.0f;
    y *= sy;
    float y2 = y2r * sy * sy;

    float xy = wred_sum64(x * y);
    // mobius_add(-x, y), c=1
    float num = (1.f - 2.f * xy + y2) * (-x) + (1.f - x2) * y;
    float den = fmaxf(1.f - 2.f * xy + x2 * y2, 1e-15f);
    float u   = num / den;

    float u2  = wred_sum64(u * u);
    float un  = fmaxf(sqrtf(u2), 1e-15f);
    float arg = fminf(un, 1.f - 1e-7f);
    float at  = 0.5f * __logf((1.f + arg) / (1.f - arg));  // atanh

    if (lane == 0) dH2[r] = 4.f * at * at;

    float lamden = fmaxf(1.f - x2, 1e-15f);  // 2/lambda
    float ls     = lamden * at / un;
    logv[((size_t)r << 6) + lane] = ls * u;
}

// ---------------- Kernel 2: fused distance+softmax+aggregation ----------------
// one block per (b,a); 256 threads = 16 dp-lanes x 16 mi-groups; 8 chunks of 64 m
__global__ __launch_bounds__(256) void k_attn(const float* __restrict__ curr_rho,
                                              const float* __restrict__ demo_rho,
                                              const float* __restrict__ dH2,
                                              float* __restrict__ alpha_ws,
                                              float* __restrict__ eout_ws) {
    __shared__ __align__(16) float lds_k[64 * 132];  // 33 KB, padded stride
    __shared__ float lds_scores[512];
    __shared__ float redmax[4];
    __shared__ float redsum[4];

    const int t    = threadIdx.x;
    const int lane = t & 63;
    const int wv   = t >> 6;
    const int dp   = t & 15;   // de part: dims [dp*8, dp*8+8)
    const int mi   = t >> 4;   // m-group: m in [mi*4, mi*4+4) per chunk
    const int blk  = blockIdx.x;
    const int b    = blk >> 6, a = blk & 63;

    float qf[8];
    {
        float4 q0 = *(const float4*)(curr_rho + (size_t)blk * DE + dp * 8);
        float4 q1 = *(const float4*)(curr_rho + (size_t)blk * DE + dp * 8 + 4);
        qf[0] = q0.x; qf[1] = q0.y; qf[2] = q0.z; qf[3] = q0.w;
        qf[4] = q1.x; qf[5] = q1.y; qf[6] = q1.z; qf[7] = q1.w;
    }
    float e_acc[8];
#pragma unroll
    for (int j = 0; j < 8; j++) e_acc[j] = 0.f;
    float gmax = -1e30f, gsum = 0.f;

    const size_t rowStride = (size_t)A_ * DE;  // 8192 floats

    for (int c = 0; c < 8; c++) {
        __syncthreads();  // previous chunk's LDS fully consumed
        const float* dbase = demo_rho + ((size_t)(b * M_ + c * 64) * A_ + a) * DE;
#pragma unroll
        for (int p = 0; p < 8; p++) {
            int unit = p * 256 + t;          // 16B units, 0..2047
            int row = unit >> 5, part = unit & 31;
            float4 v = *(const float4*)(dbase + (size_t)row * rowStride + part * 4);
            *(float4*)(&lds_k[row * 132 + part * 4]) = v;
        }
        __syncthreads();

        float sc[4], kf[4][8];
        float lmax = -1e30f;
#pragma unroll
        for (int s = 0; s < 4; s++) {
            const int m = mi * 4 + s;
            float4 k0 = *(const float4*)(&lds_k[m * 132 + dp * 8]);
            float4 k1 = *(const float4*)(&lds_k[m * 132 + dp * 8 + 4]);
            kf[s][0] = k0.x; kf[s][1] = k0.y; kf[s][2] = k0.z; kf[s][3] = k0.w;
            kf[s][4] = k1.x; kf[s][5] = k1.y; kf[s][6] = k1.z; kf[s][7] = k1.w;
            float part = 0.f;
#pragma unroll
            for (int j = 0; j < 8; j++) { float d = qf[j] - kf[s][j]; part += d * d; }
            part += __shfl_xor(part, 1, 64);
            part += __shfl_xor(part, 2, 64);
            part += __shfl_xor(part, 4, 64);
            part += __shfl_xor(part, 8, 64);   // all 16 dp-lanes now hold full e_diff
            float dv = dH2[b * M_ + c * 64 + m];
            sc[s] = -(dv + part);
            lmax  = fmaxf(lmax, sc[s]);
            if (dp == 0) lds_scores[c * 64 + m] = sc[s];
        }
        // block max of chunk
        lmax = fmaxf(lmax, __shfl_xor(lmax, 16, 64));
        lmax = fmaxf(lmax, __shfl_xor(lmax, 32, 64));
        if (lane == 0) redmax[wv] = lmax;
        __syncthreads();
        float cmax = fmaxf(fmaxf(redmax[0], redmax[1]), fmaxf(redmax[2], redmax[3]));
        float gnew = fmaxf(gmax, cmax);
        float resc = __expf(gmax - gnew);  // first chunk: exp(-1e30)=0
        gmax = gnew;
        gsum *= resc;
#pragma unroll
        for (int j = 0; j < 8; j++) e_acc[j] *= resc;

        float w[4];
        float wsum = 0.f;
#pragma unroll
        for (int s = 0; s < 4; s++) { w[s] = __expf(sc[s] - gmax); wsum += w[s]; }
        wsum += __shfl_xor(wsum, 16, 64);
        wsum += __shfl_xor(wsum, 32, 64);
        if (lane == 0) redsum[wv] = wsum;
        // aggregate from registers (no second LDS/HBM pass)
#pragma unroll
        for (int s = 0; s < 4; s++)
#pragma unroll
            for (int j = 0; j < 8; j++) e_acc[j] = fmaf(w[s], kf[s][j], e_acc[j]);
        __syncthreads();
        gsum += redsum[0] + redsum[1] + redsum[2] + redsum[3];
    }

    const float inv = 1.f / gsum;  // block-uniform
    for (int i = t; i < 512; i += 256)
        alpha_ws[(size_t)blk * 512 + i] = __expf(lds_scores[i] - gmax) * inv;
    // reduce e_acc across the 16 mi-groups via LDS (reuse chunk buffer; all kf
    // reads completed before the last in-loop barrier)
    float* rede = (float*)lds_k;  // 16 groups x stride 132 floats
    *(float4*)&rede[mi * 132 + dp * 8]     = make_float4(e_acc[0], e_acc[1], e_acc[2], e_acc[3]);
    *(float4*)&rede[mi * 132 + dp * 8 + 4] = make_float4(e_acc[4], e_acc[5], e_acc[6], e_acc[7]);
    __syncthreads();
    if (t < 128) {
        float s = 0.f;
#pragma unroll
        for (int g = 0; g < 16; g++) s += rede[g * 132 + t];
        eout_ws[(size_t)blk * 128 + t] = s * inv;
    }
}

// ---------------- Kernel 3: v = alpha@logv, exp_map, projections, LayerNorm ----------------
// one block per (b,a); 4 waves split the m-loop; wave 0 does the epilogue
__global__ __launch_bounds__(256) void k_final(const float* __restrict__ curr_hyp,
                                               const float* __restrict__ alpha_ws,
                                               const float* __restrict__ logv,
                                               const float* __restrict__ eout_ws,
                                               const float* __restrict__ We,
                                               const float* __restrict__ Wh,
                                               const float* __restrict__ gamma,
                                               const float* __restrict__ beta,
                                               float* __restrict__ out) {
    __shared__ float vpart[4][64];
    __shared__ float eh[192];  // [0:128) e_out, [128:192) h
    const int t = threadIdx.x, w = t >> 6, lane = t & 63;
    const int blk = blockIdx.x, b = blk >> 6;

    const float* arow = alpha_ws + (size_t)blk * 512;
    const float* lvb  = logv + (size_t)b * 512 * 64;
    float acc = 0.f;
#pragma unroll 8
    for (int m = w * 128; m < w * 128 + 128; ++m)
        acc = fmaf(arow[m], lvb[(size_t)m * 64 + lane], acc);
    vpart[w][lane] = acc;
    __syncthreads();

    if (w == 0) {
        float v = vpart[0][lane] + vpart[1][lane] + vpart[2][lane] + vpart[3][lane];
        const float mx = 1.0f - 1e-5f;
        float x = curr_hyp[(b << 6) + lane];
        float x2r = wred_sum64(x * x);
        float xn  = fmaxf(sqrtf(x2r), 1e-15f);
        float sx  = xn > mx ? mx / xn : 1.f;
        x *= sx;
        float x2 = x2r * sx * sx;
        float lamden = fmaxf(1.f - x2, 1e-15f);  // 2/lambda

        float v2 = wred_sum64(v * v);
        float vn = fmaxf(sqrtf(v2), 1e-15f);
        float targ   = vn / lamden;              // lambda*vnorm/2
        float e2     = __expf(2.f * targ);
        float factor = 1.f - 2.f / (e2 + 1.f);   // tanh, inf-safe
        float wvv    = v * (factor / vn);

        float w2 = wred_sum64(wvv * wvv);
        float xw = wred_sum64(x * wvv);
        float num = (1.f + 2.f * xw + w2) * x + (1.f - x2) * wvv;
        float den = fmaxf(1.f + 2.f * xw + x2 * w2, 1e-15f);
        float h   = num / den;
        float h2  = wred_sum64(h * h);
        float hn  = fmaxf(sqrtf(h2), 1e-15f);
        float shh = hn > mx ? mx / hn : 1.f;
        h *= shh;

        eh[lane]       = eout_ws[(size_t)blk * 128 + lane];
        eh[64 + lane]  = eout_ws[(size_t)blk * 128 + 64 + lane];
        eh[128 + lane] = h;
    }
    __syncthreads();

    if (w == 0) {
        float ze = 0.f;
        const float* werow = We + lane * 128;
#pragma unroll
        for (int d0 = 0; d0 < 128; d0 += 4) {
            float4 wv4 = *(const float4*)(werow + d0);
            ze = fmaf(eh[d0 + 0], wv4.x, ze);
            ze = fmaf(eh[d0 + 1], wv4.y, ze);
            ze = fmaf(eh[d0 + 2], wv4.z, ze);
            ze = fmaf(eh[d0 + 3], wv4.w, ze);
        }
        float zh = 0.f;
        const float* whrow = Wh + lane * 64;
#pragma unroll
        for (int d0 = 0; d0 < 64; d0 += 4) {
            float4 wv4 = *(const float4*)(whrow + d0);
            zh = fmaf(eh[128 + d0 + 0], wv4.x, zh);
            zh = fmaf(eh[128 + d0 + 1], wv4.y, zh);
            zh = fmaf(eh[128 + d0 + 2], wv4.z, zh);
            zh = fmaf(eh[128 + d0 + 3], wv4.w, zh);
        }
        float ssum = wred_sum64(ze + zh);
        float mean = ssum * (1.f / 128.f);
        float sq   = wred_sum64(ze * ze + zh * zh);
        float var  = sq * (1.f / 128.f) - mean * mean;
        float rinv = rsqrtf(var + 1e-5f);
        float oe = (ze - mean) * rinv * gamma[lane] + beta[lane];
        float oh = (zh - mean) * rinv * gamma[64 + lane] + beta[64 + lane];
        out[(size_t)blk * 128 + lane]      = oe;
        out[(size_t)blk * 128 + 64 + lane] = oh;
    }
}

extern "C" void kernel_launch(void* const* d_in, const int* in_sizes, int n_in,
                              void* d_out, int out_size, void* d_ws, size_t ws_size,
                              hipStream_t stream) {
    const float* curr_rho = (const float*)d_in[0];
    const float* curr_hyp = (const float*)d_in[1];
    const float* demo_rho = (const float*)d_in[2];
    const float* demo_hyp = (const float*)d_in[3];
    const float* We       = (const float*)d_in[4];
    const float* Wh       = (const float*)d_in[5];
    const float* gamma    = (const float*)d_in[6];
    const float* beta     = (const float*)d_in[7];
    float* out = (float*)d_out;

    float* ws    = (float*)d_ws;
    float* dH2   = ws;                       // 4096
    float* logv  = ws + 4096;                // 262144
    float* alpha = ws + 4096 + 262144;       // 262144
    float* eout  = ws + 4096 + 2 * 262144;   // 65536  (total ~2.3 MB)

    k_hyp<<<1024, 256, 0, stream>>>(curr_hyp, demo_hyp, dH2, logv);
    k_attn<<<512, 256, 0, stream>>>(curr_rho, demo_rho, dH2, alpha, eout);
    k_final<<<512, 256, 0, stream>>>(curr_hyp, alpha, logv, eout, We, Wh, gamma, beta, out);
}

// Round 3
// 211.669 us; speedup vs baseline: 1.0350x; 1.0350x over previous
//
#include <hip/hip_runtime.h>

#define DEV __device__ __forceinline__

constexpr int A_ = 64, DE = 128, M_ = 512, DH = 64;

DEV float wred_sum64(float v) {
#pragma unroll
    for (int o = 1; o < 64; o <<= 1) v += __shfl_xor(v, o, 64);
    return v;
}

// ---------------- Kernel 1: per-(b,m) hyperbolic dH2 + log_map ----------------
// one wave per (b,m) row; lane = dim (dh=64)
__global__ __launch_bounds__(256) void k_hyp(const float* __restrict__ curr_hyp,
                                             const float* __restrict__ demo_hyp,
                                             float* __restrict__ dH2,
                                             float* __restrict__ logv) {
    const int lane = threadIdx.x & 63;
    const int r    = (blockIdx.x << 2) + (threadIdx.x >> 6);  // [0, B*M)
    const int b    = r >> 9;                                  // M=512

    float x = curr_hyp[(b << 6) + lane];
    float y = demo_hyp[((size_t)r << 6) + lane];
    const float mx = 1.0f - 1e-5f;

    float x2r = wred_sum64(x * x);
    float xn  = fmaxf(sqrtf(x2r), 1e-15f);
    float sx  = xn > mx ? mx / xn : 1.0f;
    x *= sx;
    float x2 = x2r * sx * sx;
    float y2r = wred_sum64(y * y);
    float yn  = fmaxf(sqrtf(y2r), 1e-15f);
    float sy  = yn > mx ? mx / yn : 1.0f;
    y *= sy;
    float y2 = y2r * sy * sy;

    float xy = wred_sum64(x * y);
    float num = (1.f - 2.f * xy + y2) * (-x) + (1.f - x2) * y;
    float den = fmaxf(1.f - 2.f * xy + x2 * y2, 1e-15f);
    float u   = num / den;

    float u2  = wred_sum64(u * u);
    float un  = fmaxf(sqrtf(u2), 1e-15f);
    float arg = fminf(un, 1.f - 1e-7f);
    float at  = 0.5f * __logf((1.f + arg) / (1.f - arg));  // atanh

    if (lane == 0) dH2[r] = 4.f * at * at;

    float lamden = fmaxf(1.f - x2, 1e-15f);  // 2/lambda
    float ls     = lamden * at / un;
    logv[((size_t)r << 6) + lane] = ls * u;
}

// ---------------- Kernel 2: fully fused attention ----------------
// one block per (b,a); 512 threads = 8 waves. 16 chunks of 32 m, double-buffered.
// dp = t&15 covers de dims [dp*8, dp*8+8); mi = t>>4 is the chunk-local m (0..31).
__global__ __launch_bounds__(512, 4) void k_main(const float* __restrict__ curr_rho,
                                                 const float* __restrict__ demo_rho,
                                                 const float* __restrict__ curr_hyp,
                                                 const float* __restrict__ dH2,
                                                 const float* __restrict__ logv,
                                                 const float* __restrict__ We,
                                                 const float* __restrict__ Wh,
                                                 const float* __restrict__ gamma,
                                                 const float* __restrict__ beta,
                                                 float* __restrict__ out) {
    __shared__ __align__(16) float buf[2][32 * 132];  // 2 x 16.9 KB, padded stride
    __shared__ float lds_sc[512];
    __shared__ float lds_dh[512];
    __shared__ float redmax[8];
    __shared__ float redsum[8];
    __shared__ float vpart[8][64];
    __shared__ float eh[192];  // [0:128) e_out, [128:192) h

    const int t    = threadIdx.x;
    const int lane = t & 63;
    const int wv   = t >> 6;
    const int dp   = t & 15;
    const int mi   = t >> 4;           // 0..31
    const int blk  = blockIdx.x;
    const int b    = blk >> 6, a = blk & 63;

    lds_dh[t] = dH2[(b << 9) + t];

    float qf[8];
    {
        float4 q0 = *(const float4*)(curr_rho + (size_t)blk * DE + dp * 8);
        float4 q1 = *(const float4*)(curr_rho + (size_t)blk * DE + dp * 8 + 4);
        qf[0] = q0.x; qf[1] = q0.y; qf[2] = q0.z; qf[3] = q0.w;
        qf[4] = q1.x; qf[5] = q1.y; qf[6] = q1.z; qf[7] = q1.w;
    }

    const size_t rowStride = (size_t)A_ * DE;  // 8192 floats
    const float* base_ba = demo_rho + ((size_t)b * M_ * A_ + a) * DE;
    const int r0 = t >> 5, part = t & 31;      // staging: rows r0 and r0+16, 16B unit `part`

    // stage + commit chunk 0
    {
        float4 s0 = *(const float4*)(base_ba + (size_t)r0 * rowStride + part * 4);
        float4 s1 = *(const float4*)(base_ba + (size_t)(r0 + 16) * rowStride + part * 4);
        *(float4*)&buf[0][r0 * 132 + part * 4]        = s0;
        *(float4*)&buf[0][(r0 + 16) * 132 + part * 4] = s1;
    }

    float e_acc[8];
#pragma unroll
    for (int j = 0; j < 8; j++) e_acc[j] = 0.f;
    float gmax = -1e30f, gsum = 0.f;

    for (int c = 0; c < 16; ++c) {
        const int cur = c & 1;
        float4 n0, n1;
        if (c < 15) {  // prefetch next chunk into registers (in flight across compute)
            const float* dbase = base_ba + (size_t)(c + 1) * 32 * rowStride;
            n0 = *(const float4*)(dbase + (size_t)r0 * rowStride + part * 4);
            n1 = *(const float4*)(dbase + (size_t)(r0 + 16) * rowStride + part * 4);
        }
        __syncthreads();  // buf[cur] ready; prev chunk's readers done with buf[cur^1]

        float kf[8];
        {
            float4 k0 = *(const float4*)&buf[cur][mi * 132 + dp * 8];
            float4 k1 = *(const float4*)&buf[cur][mi * 132 + dp * 8 + 4];
            kf[0] = k0.x; kf[1] = k0.y; kf[2] = k0.z; kf[3] = k0.w;
            kf[4] = k1.x; kf[5] = k1.y; kf[6] = k1.z; kf[7] = k1.w;
        }
        float ps = 0.f;
#pragma unroll
        for (int j = 0; j < 8; j++) { float d = qf[j] - kf[j]; ps += d * d; }
        ps += __shfl_xor(ps, 1, 64);
        ps += __shfl_xor(ps, 2, 64);
        ps += __shfl_xor(ps, 4, 64);
        ps += __shfl_xor(ps, 8, 64);  // uniform over dp
        float sc = -(lds_dh[c * 32 + mi] + ps);
        if (dp == 0) lds_sc[c * 32 + mi] = sc;

        // wave-local (max, sum) pair over its 4 m values (lane bits 4,5)
        float lm = fmaxf(sc, __shfl_xor(sc, 16, 64));
        lm = fmaxf(lm, __shfl_xor(lm, 32, 64));
        float wexp = __expf(sc - lm);
        float wsum = wexp + __shfl_xor(wexp, 16, 64);
        wsum += __shfl_xor(wsum, 32, 64);
        if (lane == 0) { redmax[wv] = lm; redsum[wv] = wsum; }
        __syncthreads();

        float cmax = redmax[0];
#pragma unroll
        for (int w = 1; w < 8; w++) cmax = fmaxf(cmax, redmax[w]);
        float csum = 0.f;
#pragma unroll
        for (int w = 0; w < 8; w++) csum += redsum[w] * __expf(redmax[w] - cmax);
        float gnew = fmaxf(gmax, cmax);
        float r1 = __expf(gmax - gnew);  // first chunk: exp(-1e30)=0
        float r2 = __expf(cmax - gnew);
        gsum = gsum * r1 + csum * r2;
        float w = __expf(sc - gnew);
#pragma unroll
        for (int j = 0; j < 8; j++) e_acc[j] = fmaf(w, kf[j], e_acc[j] * r1);
        gmax = gnew;

        if (c < 15) {  // commit prefetched chunk to the other buffer (safe: consumed pre-barrier)
            *(float4*)&buf[cur ^ 1][r0 * 132 + part * 4]        = n0;
            *(float4*)&buf[cur ^ 1][(r0 + 16) * 132 + part * 4] = n1;
        }
    }

    const float inv = 1.f / gsum;  // block-uniform
    // alpha in place (own slot only; same-wave readers below)
    float al = __expf(lds_sc[t] - gmax) * inv;
    lds_sc[t] = al;

    // reduce e_acc across the 32 mi-groups
    float* rede = buf[0];
    *(float4*)&rede[mi * 132 + dp * 8]     = make_float4(e_acc[0], e_acc[1], e_acc[2], e_acc[3]);
    *(float4*)&rede[mi * 132 + dp * 8 + 4] = make_float4(e_acc[4], e_acc[5], e_acc[6], e_acc[7]);
    __syncthreads();
    if (t < 128) {
        float s = 0.f;
#pragma unroll
        for (int g = 0; g < 32; g++) s += rede[g * 132 + t];
        eh[t] = s * inv;
    }

    // v = alpha @ logv : wave wv handles m in [wv*64, wv*64+64), lane = dh dim
    {
        const float* lvb = logv + ((size_t)(b * M_) + wv * 64) * DH;
        float acc = 0.f;
#pragma unroll 8
        for (int i = 0; i < 64; ++i)
            acc = fmaf(lds_sc[wv * 64 + i], lvb[(size_t)i * DH + lane], acc);
        vpart[wv][lane] = acc;
    }
    __syncthreads();

    if (wv == 0) {
        float v = 0.f;
#pragma unroll
        for (int w = 0; w < 8; w++) v += vpart[w][lane];

        const float mx = 1.0f - 1e-5f;
        float x = curr_hyp[(b << 6) + lane];
        float x2r = wred_sum64(x * x);
        float xn  = fmaxf(sqrtf(x2r), 1e-15f);
        float sx  = xn > mx ? mx / xn : 1.f;
        x *= sx;
        float x2 = x2r * sx * sx;
        float lamden = fmaxf(1.f - x2, 1e-15f);  // 2/lambda

        float v2 = wred_sum64(v * v);
        float vn = fmaxf(sqrtf(v2), 1e-15f);
        float targ   = vn / lamden;              // lambda*vnorm/2
        float e2     = __expf(2.f * targ);
        float factor = 1.f - 2.f / (e2 + 1.f);   // tanh, inf-safe
        float wvv    = v * (factor / vn);

        float w2 = wred_sum64(wvv * wvv);
        float xw = wred_sum64(x * wvv);
        float num = (1.f + 2.f * xw + w2) * x + (1.f - x2) * wvv;
        float den = fmaxf(1.f + 2.f * xw + x2 * w2, 1e-15f);
        float h   = num / den;
        float h2  = wred_sum64(h * h);
        float hn  = fmaxf(sqrtf(h2), 1e-15f);
        float shh = hn > mx ? mx / hn : 1.f;
        h *= shh;
        eh[128 + lane] = h;  // same-wave visibility

        float ze = 0.f;
        const float* werow = We + lane * 128;
#pragma unroll
        for (int d0 = 0; d0 < 128; d0 += 4) {
            float4 wv4 = *(const float4*)(werow + d0);
            ze = fmaf(eh[d0 + 0], wv4.x, ze);
            ze = fmaf(eh[d0 + 1], wv4.y, ze);
            ze = fmaf(eh[d0 + 2], wv4.z, ze);
            ze = fmaf(eh[d0 + 3], wv4.w, ze);
        }
        float zh = 0.f;
        const float* whrow = Wh + lane * 64;
#pragma unroll
        for (int d0 = 0; d0 < 64; d0 += 4) {
            float4 wv4 = *(const float4*)(whrow + d0);
            zh = fmaf(eh[128 + d0 + 0], wv4.x, zh);
            zh = fmaf(eh[128 + d0 + 1], wv4.y, zh);
            zh = fmaf(eh[128 + d0 + 2], wv4.z, zh);
            zh = fmaf(eh[128 + d0 + 3], wv4.w, zh);
        }
        float ssum = wred_sum64(ze + zh);
        float mean = ssum * (1.f / 128.f);
        float sq   = wred_sum64(ze * ze + zh * zh);
        float var  = sq * (1.f / 128.f) - mean * mean;
        float rinv = rsqrtf(var + 1e-5f);
        float oe = (ze - mean) * rinv * gamma[lane] + beta[lane];
        float oh = (zh - mean) * rinv * gamma[64 + lane] + beta[64 + lane];
        out[(size_t)blk * 128 + lane]      = oe;
        out[(size_t)blk * 128 + 64 + lane] = oh;
    }
}

extern "C" void kernel_launch(void* const* d_in, const int* in_sizes, int n_in,
                              void* d_out, int out_size, void* d_ws, size_t ws_size,
                              hipStream_t stream) {
    const float* curr_rho = (const float*)d_in[0];
    const float* curr_hyp = (const float*)d_in[1];
    const float* demo_rho = (const float*)d_in[2];
    const float* demo_hyp = (const float*)d_in[3];
    const float* We       = (const float*)d_in[4];
    const float* Wh       = (const float*)d_in[5];
    const float* gamma    = (const float*)d_in[6];
    const float* beta     = (const float*)d_in[7];
    float* out = (float*)d_out;

    float* ws   = (float*)d_ws;
    float* dH2  = ws;            // 4096 floats
    float* logv = ws + 4096;     // 262144 floats

    k_hyp<<<1024, 256, 0, stream>>>(curr_hyp, demo_hyp, dH2, logv);
    k_main<<<512, 512, 0, stream>>>(curr_rho, demo_rho, curr_hyp, dH2, logv,
                                    We, Wh, gamma, beta, out);
}